// Round 1
// baseline (489.308 us; speedup 1.0000x reference)
//
#include <hip/hip_runtime.h>

// VACF: vel [T=10000, N=1000, 3] fp32, window W=100.
// out[t] = sum_{i<T-t} sum_j x[i][j]*x[i+t][j] / ((T-t)*C),  C = 3000.
//
// Thread = one column j. Per chunk of R=16 base rows held in registers,
// slide a circular 16-entry window over rows [i0, i0+115) and accumulate
// all 100 lags into acc[100] registers. Zero-padding rows >= T is exact.

#define T_DIM 10000
#define C_DIM 3000
#define W 100
#define R 16          // base rows per chunk; T_DIM % R == 0 (625 chunks)
#define NSEG 64       // time segments -> grid.y
#define NCGRP 12      // ceil(C_DIM / 256)

__global__ __launch_bounds__(256, 3)
void vacf_accum(const float* __restrict__ X, float* __restrict__ partial) {
    const int tid  = threadIdx.x;
    const int lane = tid & 63;
    const int wv   = tid >> 6;
    const int j    = blockIdx.x * 256 + tid;
    const bool active = (j < C_DIM);
    const int jj  = active ? j : (C_DIM - 1);   // clamp; inactive zeroed via base
    const int seg = blockIdx.y;

    float acc[W];
    #pragma unroll
    for (int t = 0; t < W; ++t) acc[t] = 0.f;

    for (int c = seg; c < T_DIM / R; c += NSEG) {
        const int i0 = c * R;
        float base[R], win[R];
        // rows i0..i0+R-1 always < T_DIM (i0 <= T_DIM - R)
        #pragma unroll
        for (int r = 0; r < R; ++r) {
            float v = X[(size_t)(i0 + r) * C_DIM + jj];
            base[r] = active ? v : 0.f;
            win[r]  = v;
        }
        // window invariant: win[m % R] holds x[i0 + m] for m in [t, t+R)
        #pragma unroll
        for (int t = 0; t < W; ++t) {
            #pragma unroll
            for (int r = 0; r < R; ++r) {
                acc[t] += base[r] * win[(t + r) % R];
            }
            if (t < W - 1) {
                const int row = i0 + R + t;                  // next window entry
                float nv = (row < T_DIM) ? X[(size_t)row * C_DIM + jj] : 0.f;
                win[t % R] = nv;
            }
        }
    }

    // per-lag wave butterfly -> 4-wave LDS combine -> 1 atomic per lag per block
    __shared__ float part[4][W];
    #pragma unroll
    for (int t = 0; t < W; ++t) {
        float v = acc[t];
        #pragma unroll
        for (int m = 1; m < 64; m <<= 1) v += __shfl_xor(v, m, 64);
        if (lane == 0) part[wv][t] = v;
    }
    __syncthreads();
    if (tid < W) {
        float s = part[0][tid] + part[1][tid] + part[2][tid] + part[3][tid];
        atomicAdd(&partial[tid], s);
    }
}

__global__ void vacf_scale(const float* __restrict__ partial, float* __restrict__ out) {
    int t = threadIdx.x;
    if (t < W) out[t] = partial[t] / ((float)(T_DIM - t) * (float)C_DIM);
}

extern "C" void kernel_launch(void* const* d_in, const int* in_sizes, int n_in,
                              void* d_out, int out_size, void* d_ws, size_t ws_size,
                              hipStream_t stream) {
    const float* X = (const float*)d_in[0];
    float* out = (float*)d_out;
    float* ws  = (float*)d_ws;

    hipMemsetAsync(ws, 0, W * sizeof(float), stream);
    dim3 grid(NCGRP, NSEG);
    vacf_accum<<<grid, 256, 0, stream>>>(X, ws);
    vacf_scale<<<1, 128, 0, stream>>>(ws, out);
}